// Round 2
// baseline (684.338 us; speedup 1.0000x reference)
//
#include <hip/hip_runtime.h>
#include <hip/hip_bf16.h>

#define N_NODES 16384
#define F_IN    512
#define N_EDGE  524288
#define H1      32
#define H2      16

typedef float f32x4 __attribute__((ext_vector_type(4)));

// ---------------- workspace layout (in 4-byte words) ----------------
#define OFF_CNT     0u          // u32 [16384]
#define OFF_ROWPTR  16448u      // u32 [16385]
#define OFF_CURSOR  32896u      // u32 [16384]
#define OFF_SRCS    49344u      // i32 [E]
#define OFF_DINV    573632u     // f32 [16384]
#define OFF_XW1     590080u     // f32 [N*32]
#define OFF_XW2     1114368u    // f32 [N*16]
#define OFF_XW3     1376512u    // f32 [N*16]
// total = 1638656 words = 6.55 MB

__device__ __forceinline__ float sigf(float x) {
    float e = __expf(-x);
    return __builtin_amdgcn_rcpf(1.0f + e);
}

// K1: histogram of dst
__global__ __launch_bounds__(256) void hist_k(const int* __restrict__ ei,
                                              unsigned* __restrict__ cnt) {
    int e = blockIdx.x * 256 + threadIdx.x;
    atomicAdd(&cnt[ei[N_EDGE + e]], 1u);
}

// K2: exclusive scan of cnt -> rowptr/cursor; dinv = rsqrt(cnt+1)
__global__ __launch_bounds__(1024) void scan_k(const unsigned* __restrict__ cnt,
                                               unsigned* __restrict__ rowptr,
                                               unsigned* __restrict__ cursor,
                                               float* __restrict__ dinv) {
    const int t = threadIdx.x;           // 1024 threads, 16 elems each
    unsigned vals[16];
    const uint4* c4 = (const uint4*)cnt;
#pragma unroll
    for (int i = 0; i < 4; ++i) {
        uint4 v = c4[t * 4 + i];
        vals[i * 4 + 0] = v.x; vals[i * 4 + 1] = v.y;
        vals[i * 4 + 2] = v.z; vals[i * 4 + 3] = v.w;
    }
    unsigned loc[16], s = 0;
#pragma unroll
    for (int i = 0; i < 16; ++i) { loc[i] = s; s += vals[i]; }

    const int lane = t & 63, w = t >> 6;       // 16 waves
    unsigned v = s;
#pragma unroll
    for (int off = 1; off < 64; off <<= 1) {
        unsigned u = __shfl_up(v, off);
        if (lane >= off) v += u;
    }
    __shared__ unsigned wtot[16];
    if (lane == 63) wtot[w] = v;
    __syncthreads();
    if (t == 0) {
        unsigned run = 0;
#pragma unroll
        for (int i = 0; i < 16; ++i) { unsigned x = wtot[i]; wtot[i] = run; run += x; }
        rowptr[N_NODES] = run;   // == E
    }
    __syncthreads();
    unsigned base = wtot[w] + v - s;    // exclusive prefix for this thread's chunk
#pragma unroll
    for (int i = 0; i < 16; ++i) {
        unsigned rp = base + loc[i];
        rowptr[t * 16 + i] = rp;
        cursor[t * 16 + i] = rp;
        dinv[t * 16 + i] = rsqrtf((float)(vals[i] + 1u));
    }
}

// K3: counting-sort fill: srcs grouped by dst
__global__ __launch_bounds__(256) void fill_k(const int* __restrict__ ei,
                                              unsigned* __restrict__ cursor,
                                              int* __restrict__ srcs) {
    int e = blockIdx.x * 256 + threadIdx.x;
    int d = ei[N_EDGE + e];
    unsigned p = atomicAdd(&cursor[d], 1u);
    srcs[p] = ei[e];
}

// K4: xw1 = x @ W1   [16384,512]x[512,32]
__global__ __launch_bounds__(256) void gemm1_k(const float* __restrict__ x,
                                               const float* __restrict__ W,
                                               float* __restrict__ xw) {
    int tid = blockIdx.x * 256 + threadIdx.x;
    int row = tid >> 3, cq = tid & 7;        // col quad
    const float4* x4 = (const float4*)(x + (size_t)row * F_IN);
    const float4* W4 = (const float4*)W;     // W[k][c]: 8 float4 per k-row
    float ax = 0.f, ay = 0.f, az = 0.f, aw = 0.f;
#pragma unroll 4
    for (int k4 = 0; k4 < F_IN / 4; ++k4) {
        float4 xv = x4[k4];
        float4 w0 = W4[(size_t)(4 * k4 + 0) * 8 + cq];
        float4 w1 = W4[(size_t)(4 * k4 + 1) * 8 + cq];
        float4 w2 = W4[(size_t)(4 * k4 + 2) * 8 + cq];
        float4 w3 = W4[(size_t)(4 * k4 + 3) * 8 + cq];
        ax = fmaf(xv.x, w0.x, ax); ay = fmaf(xv.x, w0.y, ay);
        az = fmaf(xv.x, w0.z, az); aw = fmaf(xv.x, w0.w, aw);
        ax = fmaf(xv.y, w1.x, ax); ay = fmaf(xv.y, w1.y, ay);
        az = fmaf(xv.y, w1.z, az); aw = fmaf(xv.y, w1.w, aw);
        ax = fmaf(xv.z, w2.x, ax); ay = fmaf(xv.z, w2.y, ay);
        az = fmaf(xv.z, w2.z, az); aw = fmaf(xv.z, w2.w, aw);
        ax = fmaf(xv.w, w3.x, ax); ay = fmaf(xv.w, w3.y, ay);
        az = fmaf(xv.w, w3.z, az); aw = fmaf(xv.w, w3.w, aw);
    }
    float4 o; o.x = ax; o.y = ay; o.z = az; o.w = aw;
    ((float4*)xw)[(size_t)row * 8 + cq] = o;
}

// K5: conv1 gather (h1 in LDS) fused with xw2 = h1@W2, xw3 = h1@W3
__global__ __launch_bounds__(256) void conv1_k(const float* __restrict__ xw1,
                                               const float* __restrict__ dinv,
                                               const int* __restrict__ srcs,
                                               const unsigned* __restrict__ rowptr,
                                               const float* __restrict__ b1,
                                               const float* __restrict__ W2,
                                               const float* __restrict__ W3,
                                               float* __restrict__ xw2,
                                               float* __restrict__ xw3) {
    const int t = threadIdx.x;
    const int node = blockIdx.x * 8 + (t >> 5);
    const int c = t & 31;
    unsigned e0 = rowptr[node], e1 = rowptr[node + 1];
    float sum = 0.f;
    for (unsigned e = e0; e < e1; ++e) {
        int s = srcs[e];
        sum = fmaf(xw1[(size_t)s * H1 + c], dinv[s], sum);
    }
    float di = dinv[node];
    float h = fmaf(di, sum, di * di * xw1[(size_t)node * H1 + c]) + b1[c];
    __shared__ float h1s[8][H1 + 1];
    h1s[t >> 5][c] = h;
    __syncthreads();
    const float* Wm = (c < H2) ? W2 : W3;
    int q = c & (H2 - 1);
    float acc = 0.f;
#pragma unroll
    for (int k = 0; k < H1; ++k) acc = fmaf(h1s[t >> 5][k], Wm[k * H2 + q], acc);
    if (c < H2) xw2[(size_t)node * H2 + q] = acc;
    else        xw3[(size_t)node * H2 + q] = acc;
}

// K6: conv2 gather -> mu, logvar (written straight into d_out tail)
__global__ __launch_bounds__(256) void conv2_k(const float* __restrict__ xw2,
                                               const float* __restrict__ xw3,
                                               const float* __restrict__ dinv,
                                               const int* __restrict__ srcs,
                                               const unsigned* __restrict__ rowptr,
                                               const float* __restrict__ b2,
                                               const float* __restrict__ b3,
                                               float* __restrict__ out_mu,
                                               float* __restrict__ out_lv) {
    const int t = threadIdx.x;
    const int node = blockIdx.x * 8 + (t >> 5);
    const int c = t & 31;
    const int q = c & (H2 - 1);
    const float* feat = (c < H2) ? xw2 : xw3;
    unsigned e0 = rowptr[node], e1 = rowptr[node + 1];
    float sum = 0.f;
    for (unsigned e = e0; e < e1; ++e) {
        int s = srcs[e];
        sum = fmaf(feat[(size_t)s * H2 + q], dinv[s], sum);
    }
    float di = dinv[node];
    float v = fmaf(di, sum, di * di * feat[(size_t)node * H2 + q]) +
              ((c < H2) ? b2[q] : b3[q]);
    if (c < H2) out_mu[(size_t)node * H2 + q] = v;
    else        out_lv[(size_t)node * H2 + q] = v;
}

// K7: adj = sigmoid(z @ z^T), 128x128 tile per 256-thread block
__global__ __launch_bounds__(256) void adj_k(const float* __restrict__ z,
                                             float* __restrict__ out) {
    __shared__ float4 zr[512];   // kk-XOR swizzled: [row*4 + (kk ^ (row>>3))&3]
    __shared__ float4 zc[512];
    const int t = threadIdx.x;
    const int row0 = blockIdx.y << 7, col0 = blockIdx.x << 7;
    const float4* z4 = (const float4*)z;
#pragma unroll
    for (int i = 0; i < 2; ++i) {
        int idx = t + i * 256;
        int r = idx >> 2, kk = idx & 3;
        int sw = (kk ^ (r >> 3)) & 3;
        zr[(r << 2) + sw] = z4[(size_t)(row0 + r) * 4 + kk];
        zc[(r << 2) + sw] = z4[(size_t)(col0 + r) * 4 + kk];
    }
    __syncthreads();
    const int cg = t & 15, rg = t >> 4;
    float acc[8][8];
#pragma unroll
    for (int r = 0; r < 8; ++r)
#pragma unroll
        for (int c = 0; c < 8; ++c) acc[r][c] = 0.f;

#pragma unroll
    for (int kk = 0; kk < 4; ++kk) {
        float4 a[8], b[8];
#pragma unroll
        for (int r = 0; r < 8; ++r) a[r] = zr[((rg * 8 + r) << 2) + ((kk ^ rg) & 3)];
#pragma unroll
        for (int c = 0; c < 8; ++c) b[c] = zc[((cg * 8 + c) << 2) + ((kk ^ cg) & 3)];
#pragma unroll
        for (int r = 0; r < 8; ++r)
#pragma unroll
            for (int c = 0; c < 8; ++c) {
                acc[r][c] = fmaf(a[r].x, b[c].x, acc[r][c]);
                acc[r][c] = fmaf(a[r].y, b[c].y, acc[r][c]);
                acc[r][c] = fmaf(a[r].z, b[c].z, acc[r][c]);
                acc[r][c] = fmaf(a[r].w, b[c].w, acc[r][c]);
            }
    }
#pragma unroll
    for (int r = 0; r < 8; ++r) {
        int row = row0 + rg * 8 + r;
        f32x4 o0, o1;
        o0.x = sigf(acc[r][0]); o0.y = sigf(acc[r][1]);
        o0.z = sigf(acc[r][2]); o0.w = sigf(acc[r][3]);
        o1.x = sigf(acc[r][4]); o1.y = sigf(acc[r][5]);
        o1.z = sigf(acc[r][6]); o1.w = sigf(acc[r][7]);
        f32x4* dst = (f32x4*)(out + (size_t)row * N_NODES + col0 + cg * 8);
        __builtin_nontemporal_store(o0, dst);
        __builtin_nontemporal_store(o1, dst + 1);
    }
}

extern "C" void kernel_launch(void* const* d_in, const int* in_sizes, int n_in,
                              void* d_out, int out_size, void* d_ws, size_t ws_size,
                              hipStream_t stream) {
    const float* x  = (const float*)d_in[0];
    const int*   ei = (const int*)d_in[1];
    const float* W1 = (const float*)d_in[2];
    const float* b1 = (const float*)d_in[3];
    const float* W2 = (const float*)d_in[4];
    const float* b2 = (const float*)d_in[5];
    const float* W3 = (const float*)d_in[6];
    const float* b3 = (const float*)d_in[7];
    float* out = (float*)d_out;

    unsigned* ws   = (unsigned*)d_ws;
    unsigned* cnt    = ws + OFF_CNT;
    unsigned* rowptr = ws + OFF_ROWPTR;
    unsigned* cursor = ws + OFF_CURSOR;
    int*      srcs   = (int*)(ws + OFF_SRCS);
    float*    dinv   = (float*)(ws + OFF_DINV);
    float*    xw1    = (float*)(ws + OFF_XW1);
    float*    xw2    = (float*)(ws + OFF_XW2);
    float*    xw3    = (float*)(ws + OFF_XW3);

    float* out_mu = out + (size_t)N_NODES * N_NODES;
    float* out_lv = out_mu + (size_t)N_NODES * H2;

    (void)hipMemsetAsync(cnt, 0, N_NODES * sizeof(unsigned), stream);
    hist_k<<<N_EDGE / 256, 256, 0, stream>>>(ei, cnt);
    scan_k<<<1, 1024, 0, stream>>>(cnt, rowptr, cursor, dinv);
    fill_k<<<N_EDGE / 256, 256, 0, stream>>>(ei, cursor, srcs);
    gemm1_k<<<(N_NODES * 8) / 256, 256, 0, stream>>>(x, W1, xw1);
    conv1_k<<<N_NODES / 8, 256, 0, stream>>>(xw1, dinv, srcs, rowptr, b1, W2, W3, xw2, xw3);
    conv2_k<<<N_NODES / 8, 256, 0, stream>>>(xw2, xw3, dinv, srcs, rowptr, b2, b3, out_mu, out_lv);
    adj_k<<<dim3(N_NODES / 128, N_NODES / 128), 256, 0, stream>>>(out_mu, out);
}

// Round 3
// 341.919 us; speedup vs baseline: 2.0015x; 2.0015x over previous
//
#include <hip/hip_runtime.h>
#include <hip/hip_bf16.h>

#define N_NODES 16384
#define F_IN    512
#define N_EDGE  524288
#define H1      32
#define H2      16

typedef float f32x4 __attribute__((ext_vector_type(4)));

// ---------------- workspace layout (in 4-byte words) ----------------
#define OFF_CNT     0u          // u32 [16384]
#define OFF_ROWPTR  16448u      // u32 [16385]
#define OFF_CURSOR  32896u      // u32 [16384]
#define OFF_SRCS    49344u      // i32 [E]
#define OFF_DINV    573632u     // f32 [16384]
#define OFF_XW1     590080u     // f32 [N*32]
#define OFF_XW2     1114368u    // f32 [N*16]
#define OFF_XW3     1376512u    // f32 [N*16]
// total = 1638656 words = 6.55 MB

__device__ __forceinline__ float sigf(float x) {
    float e = __expf(-x);
    return __builtin_amdgcn_rcpf(1.0f + e);
}

// K1: histogram of dst
__global__ __launch_bounds__(256) void hist_k(const int* __restrict__ ei,
                                              unsigned* __restrict__ cnt) {
    int e = blockIdx.x * 256 + threadIdx.x;
    atomicAdd(&cnt[ei[N_EDGE + e]], 1u);
}

// K2: exclusive scan of cnt -> rowptr/cursor; dinv = rsqrt(cnt+1)
__global__ __launch_bounds__(1024) void scan_k(const unsigned* __restrict__ cnt,
                                               unsigned* __restrict__ rowptr,
                                               unsigned* __restrict__ cursor,
                                               float* __restrict__ dinv) {
    const int t = threadIdx.x;           // 1024 threads, 16 elems each
    unsigned vals[16];
    const uint4* c4 = (const uint4*)cnt;
#pragma unroll
    for (int i = 0; i < 4; ++i) {
        uint4 v = c4[t * 4 + i];
        vals[i * 4 + 0] = v.x; vals[i * 4 + 1] = v.y;
        vals[i * 4 + 2] = v.z; vals[i * 4 + 3] = v.w;
    }
    unsigned loc[16], s = 0;
#pragma unroll
    for (int i = 0; i < 16; ++i) { loc[i] = s; s += vals[i]; }

    const int lane = t & 63, w = t >> 6;       // 16 waves
    unsigned v = s;
#pragma unroll
    for (int off = 1; off < 64; off <<= 1) {
        unsigned u = __shfl_up(v, off);
        if (lane >= off) v += u;
    }
    __shared__ unsigned wtot[16];
    if (lane == 63) wtot[w] = v;
    __syncthreads();
    if (t == 0) {
        unsigned run = 0;
#pragma unroll
        for (int i = 0; i < 16; ++i) { unsigned x = wtot[i]; wtot[i] = run; run += x; }
        rowptr[N_NODES] = run;   // == E
    }
    __syncthreads();
    unsigned base = wtot[w] + v - s;    // exclusive prefix for this thread's chunk
#pragma unroll
    for (int i = 0; i < 16; ++i) {
        unsigned rp = base + loc[i];
        rowptr[t * 16 + i] = rp;
        cursor[t * 16 + i] = rp;
        dinv[t * 16 + i] = rsqrtf((float)(vals[i] + 1u));
    }
}

// K3: counting-sort fill: srcs grouped by dst
__global__ __launch_bounds__(256) void fill_k(const int* __restrict__ ei,
                                              unsigned* __restrict__ cursor,
                                              int* __restrict__ srcs) {
    int e = blockIdx.x * 256 + threadIdx.x;
    int d = ei[N_EDGE + e];
    unsigned p = atomicAdd(&cursor[d], 1u);
    srcs[p] = ei[e];
}

// K4: xw1 = x @ W1   [16384,512]x[512,32]
__global__ __launch_bounds__(256) void gemm1_k(const float* __restrict__ x,
                                               const float* __restrict__ W,
                                               float* __restrict__ xw) {
    int tid = blockIdx.x * 256 + threadIdx.x;
    int row = tid >> 3, cq = tid & 7;        // col quad
    const float4* x4 = (const float4*)(x + (size_t)row * F_IN);
    const float4* W4 = (const float4*)W;     // W[k][c]: 8 float4 per k-row
    float ax = 0.f, ay = 0.f, az = 0.f, aw = 0.f;
#pragma unroll 4
    for (int k4 = 0; k4 < F_IN / 4; ++k4) {
        float4 xv = x4[k4];
        float4 w0 = W4[(size_t)(4 * k4 + 0) * 8 + cq];
        float4 w1 = W4[(size_t)(4 * k4 + 1) * 8 + cq];
        float4 w2 = W4[(size_t)(4 * k4 + 2) * 8 + cq];
        float4 w3 = W4[(size_t)(4 * k4 + 3) * 8 + cq];
        ax = fmaf(xv.x, w0.x, ax); ay = fmaf(xv.x, w0.y, ay);
        az = fmaf(xv.x, w0.z, az); aw = fmaf(xv.x, w0.w, aw);
        ax = fmaf(xv.y, w1.x, ax); ay = fmaf(xv.y, w1.y, ay);
        az = fmaf(xv.y, w1.z, az); aw = fmaf(xv.y, w1.w, aw);
        ax = fmaf(xv.z, w2.x, ax); ay = fmaf(xv.z, w2.y, ay);
        az = fmaf(xv.z, w2.z, az); aw = fmaf(xv.z, w2.w, aw);
        ax = fmaf(xv.w, w3.x, ax); ay = fmaf(xv.w, w3.y, ay);
        az = fmaf(xv.w, w3.z, az); aw = fmaf(xv.w, w3.w, aw);
    }
    float4 o; o.x = ax; o.y = ay; o.z = az; o.w = aw;
    ((float4*)xw)[(size_t)row * 8 + cq] = o;
}

// K5: conv1 gather (h1 in LDS) fused with xw2 = h1@W2, xw3 = h1@W3
__global__ __launch_bounds__(256) void conv1_k(const float* __restrict__ xw1,
                                               const float* __restrict__ dinv,
                                               const int* __restrict__ srcs,
                                               const unsigned* __restrict__ rowptr,
                                               const float* __restrict__ b1,
                                               const float* __restrict__ W2,
                                               const float* __restrict__ W3,
                                               float* __restrict__ xw2,
                                               float* __restrict__ xw3) {
    const int t = threadIdx.x;
    const int node = blockIdx.x * 8 + (t >> 5);
    const int c = t & 31;
    unsigned e0 = rowptr[node], e1 = rowptr[node + 1];
    float sum = 0.f;
    for (unsigned e = e0; e < e1; ++e) {
        int s = srcs[e];
        sum = fmaf(xw1[(size_t)s * H1 + c], dinv[s], sum);
    }
    float di = dinv[node];
    float h = fmaf(di, sum, di * di * xw1[(size_t)node * H1 + c]) + b1[c];
    __shared__ float h1s[8][H1 + 1];
    h1s[t >> 5][c] = h;
    __syncthreads();
    const float* Wm = (c < H2) ? W2 : W3;
    int q = c & (H2 - 1);
    float acc = 0.f;
#pragma unroll
    for (int k = 0; k < H1; ++k) acc = fmaf(h1s[t >> 5][k], Wm[k * H2 + q], acc);
    if (c < H2) xw2[(size_t)node * H2 + q] = acc;
    else        xw3[(size_t)node * H2 + q] = acc;
}

// K6: conv2 gather -> mu, logvar (written straight into d_out tail)
__global__ __launch_bounds__(256) void conv2_k(const float* __restrict__ xw2,
                                               const float* __restrict__ xw3,
                                               const float* __restrict__ dinv,
                                               const int* __restrict__ srcs,
                                               const unsigned* __restrict__ rowptr,
                                               const float* __restrict__ b2,
                                               const float* __restrict__ b3,
                                               float* __restrict__ out_mu,
                                               float* __restrict__ out_lv) {
    const int t = threadIdx.x;
    const int node = blockIdx.x * 8 + (t >> 5);
    const int c = t & 31;
    const int q = c & (H2 - 1);
    const float* feat = (c < H2) ? xw2 : xw3;
    unsigned e0 = rowptr[node], e1 = rowptr[node + 1];
    float sum = 0.f;
    for (unsigned e = e0; e < e1; ++e) {
        int s = srcs[e];
        sum = fmaf(feat[(size_t)s * H2 + q], dinv[s], sum);
    }
    float di = dinv[node];
    float v = fmaf(di, sum, di * di * feat[(size_t)node * H2 + q]) +
              ((c < H2) ? b2[q] : b3[q]);
    if (c < H2) out_mu[(size_t)node * H2 + q] = v;
    else        out_lv[(size_t)node * H2 + q] = v;
}

// K7: adj = sigmoid(z @ z^T), 128x128 tile per 256-thread block.
// Per-thread columns: {cg*4..cg*4+3} and {64+cg*4..+3} so each nt store
// instruction is 16 lanes x 16B = 256B contiguous per 16-lane group.
__global__ __launch_bounds__(256) void adj_k(const float* __restrict__ z,
                                             float* __restrict__ out) {
    __shared__ float4 zr[512];   // kk-XOR swizzled: [row*4 + (kk ^ (row>>3))&3]
    __shared__ float4 zc[512];
    const int t = threadIdx.x;
    const int row0 = blockIdx.y << 7, col0 = blockIdx.x << 7;
    const float4* z4 = (const float4*)z;
#pragma unroll
    for (int i = 0; i < 2; ++i) {
        int idx = t + i * 256;
        int r = idx >> 2, kk = idx & 3;
        int sw = (kk ^ (r >> 3)) & 3;
        zr[(r << 2) + sw] = z4[(size_t)(row0 + r) * 4 + kk];
        zc[(r << 2) + sw] = z4[(size_t)(col0 + r) * 4 + kk];
    }
    __syncthreads();
    const int cg = t & 15, rg = t >> 4;
    float acc[8][8];   // [r][0..3] -> col cg*4+j, [r][4..7] -> col 64+cg*4+j
#pragma unroll
    for (int r = 0; r < 8; ++r)
#pragma unroll
        for (int c = 0; c < 8; ++c) acc[r][c] = 0.f;

#pragma unroll
    for (int kk = 0; kk < 4; ++kk) {
        float4 a[8], b[8];
#pragma unroll
        for (int r = 0; r < 8; ++r) a[r] = zr[((rg * 8 + r) << 2) + ((kk ^ rg) & 3)];
#pragma unroll
        for (int j = 0; j < 4; ++j) {
            int cA = cg * 4 + j, cB = 64 + cg * 4 + j;
            b[j]     = zc[(cA << 2) + ((kk ^ (cA >> 3)) & 3)];
            b[4 + j] = zc[(cB << 2) + ((kk ^ (cB >> 3)) & 3)];
        }
#pragma unroll
        for (int r = 0; r < 8; ++r)
#pragma unroll
            for (int c = 0; c < 8; ++c) {
                acc[r][c] = fmaf(a[r].x, b[c].x, acc[r][c]);
                acc[r][c] = fmaf(a[r].y, b[c].y, acc[r][c]);
                acc[r][c] = fmaf(a[r].z, b[c].z, acc[r][c]);
                acc[r][c] = fmaf(a[r].w, b[c].w, acc[r][c]);
            }
    }
#pragma unroll
    for (int r = 0; r < 8; ++r) {
        int row = row0 + rg * 8 + r;
        f32x4 o0, o1;
        o0.x = sigf(acc[r][0]); o0.y = sigf(acc[r][1]);
        o0.z = sigf(acc[r][2]); o0.w = sigf(acc[r][3]);
        o1.x = sigf(acc[r][4]); o1.y = sigf(acc[r][5]);
        o1.z = sigf(acc[r][6]); o1.w = sigf(acc[r][7]);
        float* base = out + (size_t)row * N_NODES + col0;
        __builtin_nontemporal_store(o0, (f32x4*)(base + cg * 4));
        __builtin_nontemporal_store(o1, (f32x4*)(base + 64 + cg * 4));
    }
}

extern "C" void kernel_launch(void* const* d_in, const int* in_sizes, int n_in,
                              void* d_out, int out_size, void* d_ws, size_t ws_size,
                              hipStream_t stream) {
    const float* x  = (const float*)d_in[0];
    const int*   ei = (const int*)d_in[1];
    const float* W1 = (const float*)d_in[2];
    const float* b1 = (const float*)d_in[3];
    const float* W2 = (const float*)d_in[4];
    const float* b2 = (const float*)d_in[5];
    const float* W3 = (const float*)d_in[6];
    const float* b3 = (const float*)d_in[7];
    float* out = (float*)d_out;

    unsigned* ws   = (unsigned*)d_ws;
    unsigned* cnt    = ws + OFF_CNT;
    unsigned* rowptr = ws + OFF_ROWPTR;
    unsigned* cursor = ws + OFF_CURSOR;
    int*      srcs   = (int*)(ws + OFF_SRCS);
    float*    dinv   = (float*)(ws + OFF_DINV);
    float*    xw1    = (float*)(ws + OFF_XW1);
    float*    xw2    = (float*)(ws + OFF_XW2);
    float*    xw3    = (float*)(ws + OFF_XW3);

    float* out_mu = out + (size_t)N_NODES * N_NODES;
    float* out_lv = out_mu + (size_t)N_NODES * H2;

    (void)hipMemsetAsync(cnt, 0, N_NODES * sizeof(unsigned), stream);
    hist_k<<<N_EDGE / 256, 256, 0, stream>>>(ei, cnt);
    scan_k<<<1, 1024, 0, stream>>>(cnt, rowptr, cursor, dinv);
    fill_k<<<N_EDGE / 256, 256, 0, stream>>>(ei, cursor, srcs);
    gemm1_k<<<(N_NODES * 8) / 256, 256, 0, stream>>>(x, W1, xw1);
    conv1_k<<<N_NODES / 8, 256, 0, stream>>>(xw1, dinv, srcs, rowptr, b1, W2, W3, xw2, xw3);
    conv2_k<<<N_NODES / 8, 256, 0, stream>>>(xw2, xw3, dinv, srcs, rowptr, b2, b3, out_mu, out_lv);
    adj_k<<<dim3(N_NODES / 128, N_NODES / 128), 256, 0, stream>>>(out_mu, out);
}